// Round 3
// baseline (404.898 us; speedup 1.0000x reference)
//
#include <hip/hip_runtime.h>

#define NCOLS 16
#define NPAIR 120   // C(16,2)
#define NTRIP 560   // C(16,3)
#define OUTC  (NCOLS + NPAIR + NTRIP)   // 696
#define WPB   4     // waves per block (256 threads)

struct Tables {
    unsigned short pair_ij[NPAIR];  // i | (j<<8)
    unsigned short trip[NTRIP];     // pid | (k<<8)
};

constexpr Tables make_tables() {
    Tables t{};
    int p = 0;
    for (int i = 0; i < NCOLS; ++i)
        for (int j = i + 1; j < NCOLS; ++j)
            t.pair_ij[p++] = (unsigned short)(i | (j << 8));
    int q = 0;
    for (int i = 0; i < NCOLS; ++i)
        for (int j = i + 1; j < NCOLS; ++j)
            for (int k = j + 1; k < NCOLS; ++k) {
                // lexicographic pair rank of (i,j)
                int pid = i * (2 * NCOLS - i - 1) / 2 + (j - i - 1);
                t.trip[q++] = (unsigned short)(pid | (k << 8));
            }
    return t;
}

__device__ const Tables d_tbl = make_tables();

__device__ __forceinline__ float tnorm(float a, float b, float lam) {
    // T(a,b) = a*b / max(a, b, lam); fmaxf(fmaxf(..)) fuses to v_max3_f32
    float m = fmaxf(fmaxf(a, b), lam);
    return a * b * __builtin_amdgcn_rcpf(m);
}

__global__ __launch_bounds__(256) void dubois_kernel(
    const float* __restrict__ x, const float* __restrict__ lam_p,
    float* __restrict__ out, int B, int iters, int nwaves)
{
    __shared__ float s_x[WPB][NCOLS];
    __shared__ float s_pair[WPB][NPAIR];

    const int lane = threadIdx.x & 63;
    const int ws   = threadIdx.x >> 6;
    const int gwave = blockIdx.x * WPB + ws;
    const float lam = lam_p[0];

    for (int it = 0; it < iters; ++it) {
        const int row = gwave + it * nwaves;
        const bool active = row < B;

        // stage row + identity columns
        if (active && lane < NCOLS) {
            float v = x[(size_t)row * NCOLS + lane];
            s_x[ws][lane] = v;
            out[(size_t)row * OUTC + lane] = v;
        }
        __syncthreads();

        // pairs (also cached in LDS for the triples)
        if (active) {
            float* orow = out + (size_t)row * OUTC;
            #pragma unroll
            for (int r = 0; r < 2; ++r) {
                int p = lane + r * 64;
                if (p < NPAIR) {
                    unsigned int ij = d_tbl.pair_ij[p];
                    float a = s_x[ws][ij & 15];
                    float b = s_x[ws][ij >> 8];
                    float v = tnorm(a, b, lam);
                    s_pair[ws][p] = v;
                    orow[NCOLS + p] = v;
                }
            }
        }
        __syncthreads();

        // triples: T(pair(i,j), x_k)
        if (active) {
            float* orow = out + (size_t)row * OUTC;
            #pragma unroll
            for (int r = 0; r < 9; ++r) {
                int t = lane + r * 64;
                if (t < NTRIP) {
                    unsigned int pk = d_tbl.trip[t];
                    float a = s_pair[ws][pk & 255];
                    float c = s_x[ws][pk >> 8];
                    orow[NCOLS + NPAIR + t] = tnorm(a, c, lam);
                }
            }
        }
        __syncthreads();
    }
}

extern "C" void kernel_launch(void* const* d_in, const int* in_sizes, int n_in,
                              void* d_out, int out_size, void* d_ws, size_t ws_size,
                              hipStream_t stream) {
    const float* x   = (const float*)d_in[0];
    const float* lam = (const float*)d_in[1];
    float* out = (float*)d_out;

    const int B = in_sizes[0] / NCOLS;          // 131072
    const int blocks = 2048;                    // 8 blocks/CU on 256 CUs
    const int nwaves = blocks * WPB;            // 8192 waves
    const int iters  = (B + nwaves - 1) / nwaves;

    dubois_kernel<<<blocks, 256, 0, stream>>>(x, lam, out, B, iters, nwaves);
}

// Round 5
// 397.780 us; speedup vs baseline: 1.0179x; 1.0179x over previous
//
#include <hip/hip_runtime.h>

#define NCOLS 16
#define NPAIR 120                      // C(16,2)
#define NTRIP 560                      // C(16,3)
#define OUTC  (NCOLS + NPAIR + NTRIP)  // 696
#define NREG  11                       // ceil(696/64) store slots per row

// Unified column table: entry = i | j<<8 | k<<16 | op<<24
//   op 0: identity -> x[i]
//   op 1: pair     -> T(x[i], x[j])
//   op 2: triple   -> T(T(x[i], x[j]), x[k])
struct ColTab { unsigned int c[NREG * 64]; };  // 704, padded

constexpr ColTab make_cols() {
    ColTab t{};
    int q = 0;
    for (int i = 0; i < NCOLS; ++i)
        t.c[q++] = (unsigned)i | ((unsigned)i << 8) | ((unsigned)i << 16) | (0u << 24);
    for (int i = 0; i < NCOLS; ++i)
        for (int j = i + 1; j < NCOLS; ++j)
            t.c[q++] = (unsigned)i | ((unsigned)j << 8) | ((unsigned)j << 16) | (1u << 24);
    for (int i = 0; i < NCOLS; ++i)
        for (int j = i + 1; j < NCOLS; ++j)
            for (int k = j + 1; k < NCOLS; ++k)
                t.c[q++] = (unsigned)i | ((unsigned)j << 8) | ((unsigned)k << 16) | (2u << 24);
    while (q < NREG * 64) t.c[q++] = 0u;  // padding (never stored)
    return t;
}

__device__ const ColTab d_cols = make_cols();

__device__ __forceinline__ float tnorm(float a, float b, float lam) {
    // T(a,b) = a*b / max(a, b, lam); fmaxf(fmaxf(..)) -> v_max3_f32
    float m = fmaxf(fmaxf(a, b), lam);
    return a * b * __builtin_amdgcn_rcpf(m);
}

__global__ __launch_bounds__(256) void dubois_kernel(
    const float* __restrict__ x, const float* __restrict__ lam_p,
    float* __restrict__ out, int B, int iters, int nwaves)
{
    const int lane  = threadIdx.x & 63;
    const int gwave = (blockIdx.x * blockDim.x + threadIdx.x) >> 6;
    const float lam = lam_p[0];

    // hoist the column table into registers once (lane-indexed, row-invariant)
    unsigned int tab[NREG];
    #pragma unroll
    for (int r = 0; r < NREG; ++r)
        tab[r] = d_cols.c[lane + r * 64];

    for (int it = 0; it < iters; ++it) {
        const int row = gwave + it * nwaves;
        if (row >= B) break;

        // lanes 0..15 hold the row; 16..63 replicate (same 64B line, broadcast)
        float v = x[(size_t)row * NCOLS + (lane & 15)];
        float* __restrict__ orow = out + (size_t)row * OUTC;

        float res[NREG];
        #pragma unroll
        for (int r = 0; r < NREG; ++r) {
            unsigned int e = tab[r];
            float a  = __shfl(v, (int)(e & 255u));
            float b  = __shfl(v, (int)((e >> 8) & 255u));
            float c  = __shfl(v, (int)((e >> 16) & 255u));
            float t1 = tnorm(a, b, lam);
            float t2 = tnorm(t1, c, lam);
            unsigned int op = e >> 24;
            res[r] = (op == 0u) ? a : ((op == 1u) ? t1 : t2);
        }

        // 10 full wave-stores + 1 masked (lane<56): 98.9% dense, no barriers
        #pragma unroll
        for (int r = 0; r < NREG; ++r) {
            int c = lane + r * 64;
            if (r < NREG - 1 || c < OUTC)   // r<10 folds at compile time
                orow[c] = res[r];
        }
    }
}

extern "C" void kernel_launch(void* const* d_in, const int* in_sizes, int n_in,
                              void* d_out, int out_size, void* d_ws, size_t ws_size,
                              hipStream_t stream) {
    const float* x   = (const float*)d_in[0];
    const float* lam = (const float*)d_in[1];
    float* out = (float*)d_out;

    const int B = in_sizes[0] / NCOLS;     // 131072
    const int threads = 256;
    const int blocks  = 2048;              // 8 blocks/CU -> full occupancy
    const int nwaves  = blocks * (threads / 64);   // 8192 waves
    const int iters   = (B + nwaves - 1) / nwaves; // 16

    dubois_kernel<<<blocks, threads, 0, stream>>>(x, lam, out, B, iters, nwaves);
}